// Round 3
// baseline (281.908 us; speedup 1.0000x reference)
//
#include <hip/hip_runtime.h>

typedef __attribute__((ext_vector_type(8))) short short8;
typedef __attribute__((ext_vector_type(4))) float f32x4;

// Pack two fp32 into two bf16 (round-half-up) in one u32: 3 VALU ops per pair.
__device__ __forceinline__ unsigned pack2bf(float x0, float x1) {
    unsigned u0 = __float_as_uint(x0) + 0x8000u;
    unsigned u1 = __float_as_uint(x1) + 0x8000u;
    return __builtin_amdgcn_perm(u1, u0, 0x07060302u);  // {u1.hi16, u0.hi16}
}

// Convert W (mul x mul, row-major [u][w]) to bf16, fold in scale, store in
// MFMA-B-fragment order: frag (cb,kb) holds B[k][n] for n=cb*16+(l&15),
// k=kb*32+(l>>4)*8+j ; element addr = ((cb*NKB+kb)*64 + lane)*8 + j.
__global__ __launch_bounds__(256) void prep_w(const float* __restrict__ W,
                                              unsigned short* __restrict__ dst,
                                              int mul, float scale) {
    int idx = blockIdx.x * 256 + threadIdx.x;
    if (idx >= mul * mul) return;
    int u = idx >> (mul == 256 ? 8 : (mul == 128 ? 7 : 6));
    int w = idx - u * mul;
    int nkb = mul >> 5;
    int cb = w >> 4, kb = u >> 5;
    int lane = ((u >> 3) & 3) * 16 + (w & 15);
    int j = u & 7;
    unsigned uv = __float_as_uint(W[idx] * scale) + 0x8000u;
    dst[(((cb * nkb + kb) * 64 + lane) << 3) + j] = (unsigned short)(uv >> 16);
}

// Load one lane's contiguous u-octet (8 u's x D floats) and de-interleave into
// D A-fragments (frag d, element j = x[u=octet_base+j][d]).
template <int D>
__device__ __forceinline__ void pack_a(const float* __restrict__ p, short8* __restrict__ out) {
    float buf[8 * D];
#pragma unroll
    for (int v = 0; v < 2 * D; ++v) {
        f32x4 t = *reinterpret_cast<const f32x4*>(p + v * 4);
        buf[v * 4 + 0] = t[0]; buf[v * 4 + 1] = t[1];
        buf[v * 4 + 2] = t[2]; buf[v * 4 + 3] = t[3];
    }
#pragma unroll
    for (int d = 0; d < D; ++d) {
        union { short8 s8; unsigned u32[4]; } fr;
#pragma unroll
        for (int jj = 0; jj < 4; ++jj)
            fr.u32[jj] = pack2bf(buf[(2 * jj) * D + d], buf[(2 * jj + 1) * D + d]);
        out[d] = fr.s8;
    }
}

// One fused kernel, three blockIdx segments running concurrently.
// All segments: B fragments register-resident across the wave's tiles.
__global__ __launch_bounds__(256, 4) void lin_main(const float* __restrict__ in,
                                                   const unsigned short* __restrict__ wf0,
                                                   const unsigned short* __restrict__ wf1,
                                                   const unsigned short* __restrict__ wf2,
                                                   const float* __restrict__ bias,
                                                   float* __restrict__ out) {
    const int w = threadIdx.x >> 6;
    const int lane = threadIdx.x & 63;
    const int lm = lane & 15, lg = lane >> 4;
    const int g = blockIdx.x;

    if (g < 1563) {
        // ---- seg0: MUL=256, D=1, OFF=0, bias. 4 waves share 4 tiles; wave owns cbs w*4..w*4+3.
        short8 b[4][8];
#pragma unroll
        for (int c = 0; c < 4; ++c)
#pragma unroll
            for (int kb = 0; kb < 8; ++kb)
                b[c][kb] = *reinterpret_cast<const short8*>(wf0 + ((((w * 4 + c) * 8 + kb) * 64 + lane) << 3));
        float bv[4];
#pragma unroll
        for (int c = 0; c < 4; ++c) bv[c] = bias[(w * 4 + c) * 16 + lm];
#pragma unroll 2
        for (int t = 0; t < 4; ++t) {
            int tile = g * 4 + t;
            if (tile >= 6250) break;
            const float* rp = in + (tile * 16 + lm) * 960;
            short8 a[8];
#pragma unroll
            for (int kb = 0; kb < 8; ++kb)
                pack_a<1>(rp + kb * 32 + lg * 8, &a[kb]);
#pragma unroll
            for (int c = 0; c < 4; ++c) {
                f32x4 acc = {0.f, 0.f, 0.f, 0.f};
#pragma unroll
                for (int kb = 0; kb < 8; ++kb)
                    acc = __builtin_amdgcn_mfma_f32_16x16x32_bf16(a[kb], b[c][kb], acc, 0, 0, 0);
#pragma unroll
                for (int jj = 0; jj < 4; ++jj)
                    out[(tile * 16 + lg * 4 + jj) * 960 + (w * 4 + c) * 16 + lm] = acc[jj] + bv[c];
            }
        }
    } else if (g < 3126) {
        // ---- seg1: MUL=128, D=3, OFF=256. Wave (stream=w>>1, half=w&1): 2 tiles, 4 cbs.
        const int g1 = g - 1563, str = w >> 1, hf = w & 1;
        short8 b[4][4];
#pragma unroll
        for (int c = 0; c < 4; ++c)
#pragma unroll
            for (int kb = 0; kb < 4; ++kb)
                b[c][kb] = *reinterpret_cast<const short8*>(wf1 + ((((hf * 4 + c) * 4 + kb) * 64 + lane) << 3));
#pragma unroll 2
        for (int t = 0; t < 2; ++t) {
            int tile = g1 * 4 + str * 2 + t;
            if (tile >= 6250) break;
            const float* rp = in + (tile * 16 + lm) * 960 + 256;
            short8 a[4][3];
#pragma unroll
            for (int kb = 0; kb < 4; ++kb)
                pack_a<3>(rp + (kb * 32 + lg * 8) * 3, a[kb]);
#pragma unroll
            for (int c = 0; c < 4; ++c) {
                f32x4 acc[3];
#pragma unroll
                for (int d = 0; d < 3; ++d) acc[d] = (f32x4){0.f, 0.f, 0.f, 0.f};
#pragma unroll
                for (int kb = 0; kb < 4; ++kb)
#pragma unroll
                    for (int d = 0; d < 3; ++d)
                        acc[d] = __builtin_amdgcn_mfma_f32_16x16x32_bf16(a[kb][d], b[c][kb], acc[d], 0, 0, 0);
#pragma unroll
                for (int jj = 0; jj < 4; ++jj) {
                    float* op = out + (tile * 16 + lg * 4 + jj) * 960 + 256 + ((hf * 4 + c) * 16 + lm) * 3;
#pragma unroll
                    for (int d = 0; d < 3; ++d) op[d] = acc[d][jj];
                }
            }
        }
    } else {
        // ---- seg2: MUL=64, D=5, OFF=640. Wave: 1 tile, all 4 cbs.
        const int g2 = g - 3126;
        short8 b[4][2];
#pragma unroll
        for (int c = 0; c < 4; ++c)
#pragma unroll
            for (int kb = 0; kb < 2; ++kb)
                b[c][kb] = *reinterpret_cast<const short8*>(wf2 + (((c * 2 + kb) * 64 + lane) << 3));
        int tile = g2 * 4 + w;
        if (tile < 6250) {
            const float* rp = in + (tile * 16 + lm) * 960 + 640;
            short8 a[2][5];
#pragma unroll
            for (int kb = 0; kb < 2; ++kb)
                pack_a<5>(rp + (kb * 32 + lg * 8) * 5, a[kb]);
#pragma unroll
            for (int c = 0; c < 4; ++c) {
                f32x4 acc[5];
#pragma unroll
                for (int d = 0; d < 5; ++d) acc[d] = (f32x4){0.f, 0.f, 0.f, 0.f};
#pragma unroll
                for (int kb = 0; kb < 2; ++kb)
#pragma unroll
                    for (int d = 0; d < 5; ++d)
                        acc[d] = __builtin_amdgcn_mfma_f32_16x16x32_bf16(a[kb][d], b[c][kb], acc[d], 0, 0, 0);
#pragma unroll
                for (int jj = 0; jj < 4; ++jj) {
                    float* op = out + (tile * 16 + lg * 4 + jj) * 960 + 640 + (c * 16 + lm) * 5;
#pragma unroll
                    for (int d = 0; d < 5; ++d) op[d] = acc[d][jj];
                }
            }
        }
    }
}

extern "C" void kernel_launch(void* const* d_in, const int* in_sizes, int n_in,
                              void* d_out, int out_size, void* d_ws, size_t ws_size,
                              hipStream_t stream) {
    (void)in_sizes; (void)n_in; (void)out_size; (void)ws_size;
    const float* x  = (const float*)d_in[0];
    const float* W0 = (const float*)d_in[1];
    const float* W1 = (const float*)d_in[2];
    const float* W2 = (const float*)d_in[3];
    const float* b  = (const float*)d_in[4];
    float* out = (float*)d_out;
    unsigned short* wf = (unsigned short*)d_ws;  // 65536 + 16384 + 4096 bf16 = 168 KB

    prep_w<<<256, 256, 0, stream>>>(W0, wf,         256, 0.0625f);               // 1/sqrt(256)
    prep_w<<<64,  256, 0, stream>>>(W1, wf + 65536, 128, 0.08838834764831845f);  // 1/sqrt(128)
    prep_w<<<16,  256, 0, stream>>>(W2, wf + 81920, 64,  0.125f);                // 1/sqrt(64)
    lin_main<<<4689, 256, 0, stream>>>(x, wf, wf + 65536, wf + 81920, b, out);
}

// Round 4
// 173.362 us; speedup vs baseline: 1.6261x; 1.6261x over previous
//
#include <hip/hip_runtime.h>

typedef __attribute__((ext_vector_type(8))) short short8;
typedef __attribute__((ext_vector_type(4))) float f32x4;

// Pack two fp32 into two bf16 (round-half-up) in one u32: 3 VALU ops per pair.
__device__ __forceinline__ unsigned pack2bf(float x0, float x1) {
    unsigned u0 = __float_as_uint(x0) + 0x8000u;
    unsigned u1 = __float_as_uint(x1) + 0x8000u;
    return __builtin_amdgcn_perm(u1, u0, 0x07060302u);  // {u1.hi16, u0.hi16}
}

// Convert W (mul x mul, row-major [u][w]) to bf16, fold in scale, store in
// MFMA-B-fragment order: frag (cb,kb) holds B[k][n] for n=cb*16+(l&15),
// k=kb*32+(l>>4)*8+j ; element addr = ((cb*NKB+kb)*64 + lane)*8 + j.
__global__ __launch_bounds__(256) void prep_w(const float* __restrict__ W,
                                              unsigned short* __restrict__ dst,
                                              int mul, float scale) {
    int idx = blockIdx.x * 256 + threadIdx.x;
    if (idx >= mul * mul) return;
    int u = idx >> (mul == 256 ? 8 : (mul == 128 ? 7 : 6));
    int w = idx - u * mul;
    int nkb = mul >> 5;
    int cb = w >> 4, kb = u >> 5;
    int lane = ((u >> 3) & 3) * 16 + (w & 15);
    int j = u & 7;
    unsigned uv = __float_as_uint(W[idx] * scale) + 0x8000u;
    dst[(((cb * nkb + kb) * 64 + lane) << 3) + j] = (unsigned short)(uv >> 16);
}

// Read 2*D swizzled 16B chunks of row `lrow` starting at logical chunk c0,
// de-interleave by d into D A-fragments (elem j = x[u_octet_base + j][d]).
template <int D>
__device__ __forceinline__ void pack_from_lds(const float* __restrict__ lrow, int xr, int c0,
                                              short8* __restrict__ out) {
    float buf[8 * D];
#pragma unroll
    for (int v = 0; v < 2 * D; ++v) {
        f32x4 t = *reinterpret_cast<const f32x4*>(lrow + (((c0 + v) ^ xr) << 2));
        buf[v * 4 + 0] = t[0]; buf[v * 4 + 1] = t[1];
        buf[v * 4 + 2] = t[2]; buf[v * 4 + 3] = t[3];
    }
#pragma unroll
    for (int d = 0; d < D; ++d) {
        union { short8 s8; unsigned u[4]; } fr;
#pragma unroll
        for (int jj = 0; jj < 4; ++jj)
            fr.u[jj] = pack2bf(buf[(2 * jj) * D + d], buf[(2 * jj + 1) * D + d]);
        out[d] = fr.s8;
    }
}

// grid = 256 blocks (1/CU, LDS-limited), 4 waves/block. Block owns a contiguous
// run of 16-row tiles; 2-phase global_load_lds double-buffer streaming.
__global__ __launch_bounds__(256, 1) void lin_main(const float* __restrict__ in,
                                                   const unsigned short* __restrict__ wf0,
                                                   const unsigned short* __restrict__ wf1,
                                                   const unsigned short* __restrict__ wf2,
                                                   const float* __restrict__ bias,
                                                   float* __restrict__ out) {
    __shared__ float lds[2][15360];  // 2 x 16 rows x 960 f32 = 122880 B
    const int w = threadIdx.x >> 6;
    const int lane = threadIdx.x & 63;
    const int lm = lane & 15, lg = lane >> 4, xr = lm & 7;

    // ---- register-resident B fragments (whole W, split by cb across waves)
    short8 b0[4][8], b1[2][4], b2[2];
#pragma unroll
    for (int c = 0; c < 4; ++c)
#pragma unroll
        for (int kb = 0; kb < 8; ++kb)
            b0[c][kb] = *reinterpret_cast<const short8*>(wf0 + ((((w * 4 + c) * 8 + kb) * 64 + lane) << 3));
#pragma unroll
    for (int c = 0; c < 2; ++c)
#pragma unroll
        for (int kb = 0; kb < 4; ++kb)
            b1[c][kb] = *reinterpret_cast<const short8*>(wf1 + ((((w * 2 + c) * 4 + kb) * 64 + lane) << 3));
#pragma unroll
    for (int kb = 0; kb < 2; ++kb)
        b2[kb] = *reinterpret_cast<const short8*>(wf2 + (((w * 2 + kb) * 64 + lane) << 3));
    float bv[4];
#pragma unroll
    for (int c = 0; c < 4; ++c) bv[c] = bias[(w * 4 + c) * 16 + lm];

    // ---- per-lane staging source offsets (bytes from tile base), pre-swizzled:
    // LDS slot (row,c) <- global chunk (row, c ^ (row&7)); slot = w*960 + i*64 + lane.
    int srcoff[15];
#pragma unroll
    for (int i = 0; i < 15; ++i) {
        int s = w * 960 + i * 64 + lane;
        int row = (int)(((long long)s * 17477) >> 22);  // s / 240
        int c = s - row * 240;
        srcoff[i] = (row * 240 + (c ^ (row & 7))) << 4;
    }

    const int b = blockIdx.x;
    const int nt = (b < 106) ? 25 : 24;          // 6250 tiles over 256 blocks
    const int t0 = b * 24 + (b < 106 ? b : 106); // contiguous tile range

    // ---- prologue: stage first tile
    {
        const char* tb = (const char*)in + (size_t)t0 * 61440;
        char* sd = (char*)&lds[0][0] + w * 15360;
#pragma unroll
        for (int i = 0; i < 15; ++i)
            __builtin_amdgcn_global_load_lds(
                (const __attribute__((address_space(1))) void*)(tb + srcoff[i]),
                (__attribute__((address_space(3))) void*)(sd + i * 1024), 16, 0, 0);
    }
    __syncthreads();

    for (int k = 0; k < nt; ++k) {
        const int par = k & 1;
        // ---- stage next tile into the other buffer (loads stay in flight over compute)
        if (k + 1 < nt) {
            const char* tb = (const char*)in + (size_t)(t0 + k + 1) * 61440;
            char* sd = (char*)&lds[0][0] + (par ^ 1) * 61440 + w * 15360;
#pragma unroll
            for (int i = 0; i < 15; ++i)
                __builtin_amdgcn_global_load_lds(
                    (const __attribute__((address_space(1))) void*)(tb + srcoff[i]),
                    (__attribute__((address_space(3))) void*)(sd + i * 1024), 16, 0, 0);
        }
        // ---- compute current tile from LDS
        const float* lrow = &lds[0][0] + par * 15360 + lm * 960;
        const int trow = (t0 + k) * 16;
        {  // blk0: MUL=256, D=1, cols [0,256), bias
            short8 a[8];
#pragma unroll
            for (int kb = 0; kb < 8; ++kb)
                pack_from_lds<1>(lrow, xr, 8 * kb + 2 * lg, &a[kb]);
#pragma unroll
            for (int c = 0; c < 4; ++c) {
                f32x4 acc = {0.f, 0.f, 0.f, 0.f};
#pragma unroll
                for (int kb = 0; kb < 8; ++kb)
                    acc = __builtin_amdgcn_mfma_f32_16x16x32_bf16(a[kb], b0[c][kb], acc, 0, 0, 0);
#pragma unroll
                for (int jj = 0; jj < 4; ++jj)
                    out[(size_t)(trow + lg * 4 + jj) * 960 + (w * 4 + c) * 16 + lm] = acc[jj] + bv[c];
            }
        }
        {  // blk1: MUL=128, D=3, cols [256,640)
            short8 a[4][3];
#pragma unroll
            for (int kb = 0; kb < 4; ++kb)
                pack_from_lds<3>(lrow, xr, 64 + 24 * kb + 6 * lg, a[kb]);
#pragma unroll
            for (int c = 0; c < 2; ++c) {
                f32x4 acc[3];
#pragma unroll
                for (int d = 0; d < 3; ++d) acc[d] = (f32x4){0.f, 0.f, 0.f, 0.f};
#pragma unroll
                for (int kb = 0; kb < 4; ++kb)
#pragma unroll
                    for (int d = 0; d < 3; ++d)
                        acc[d] = __builtin_amdgcn_mfma_f32_16x16x32_bf16(a[kb][d], b1[c][kb], acc[d], 0, 0, 0);
#pragma unroll
                for (int jj = 0; jj < 4; ++jj) {
                    float* op = out + (size_t)(trow + lg * 4 + jj) * 960 + 256 + ((w * 2 + c) * 16 + lm) * 3;
#pragma unroll
                    for (int d = 0; d < 3; ++d) op[d] = acc[d][jj];
                }
            }
        }
        {  // blk2: MUL=64, D=5, cols [640,960)
            short8 a[2][5];
#pragma unroll
            for (int kb = 0; kb < 2; ++kb)
                pack_from_lds<5>(lrow, xr, 160 + 40 * kb + 10 * lg, a[kb]);
            f32x4 acc[5];
#pragma unroll
            for (int d = 0; d < 5; ++d) acc[d] = (f32x4){0.f, 0.f, 0.f, 0.f};
#pragma unroll
            for (int kb = 0; kb < 2; ++kb)
#pragma unroll
                for (int d = 0; d < 5; ++d)
                    acc[d] = __builtin_amdgcn_mfma_f32_16x16x32_bf16(a[kb][d], b2[kb], acc[d], 0, 0, 0);
#pragma unroll
            for (int jj = 0; jj < 4; ++jj) {
                float* op = out + (size_t)(trow + lg * 4 + jj) * 960 + 640 + (w * 16 + lm) * 5;
#pragma unroll
                for (int d = 0; d < 5; ++d) op[d] = acc[d][jj];
            }
        }
        __syncthreads();  // vmcnt(0)+barrier: next-tile stage drained, buffer reusable
    }
}

extern "C" void kernel_launch(void* const* d_in, const int* in_sizes, int n_in,
                              void* d_out, int out_size, void* d_ws, size_t ws_size,
                              hipStream_t stream) {
    (void)in_sizes; (void)n_in; (void)out_size; (void)ws_size;
    const float* x  = (const float*)d_in[0];
    const float* W0 = (const float*)d_in[1];
    const float* W1 = (const float*)d_in[2];
    const float* W2 = (const float*)d_in[3];
    const float* b  = (const float*)d_in[4];
    float* out = (float*)d_out;
    unsigned short* wf = (unsigned short*)d_ws;  // 65536 + 16384 + 4096 bf16 = 168 KB

    prep_w<<<256, 256, 0, stream>>>(W0, wf,         256, 0.0625f);               // 1/sqrt(256)
    prep_w<<<64,  256, 0, stream>>>(W1, wf + 65536, 128, 0.08838834764831845f);  // 1/sqrt(128)
    prep_w<<<16,  256, 0, stream>>>(W2, wf + 81920, 64,  0.125f);                // 1/sqrt(64)
    lin_main<<<256, 256, 0, stream>>>(x, wf, wf + 65536, wf + 81920, b, out);
}

// Round 5
// 168.878 us; speedup vs baseline: 1.6693x; 1.0266x over previous
//
#include <hip/hip_runtime.h>

typedef __attribute__((ext_vector_type(8))) short short8;
typedef __attribute__((ext_vector_type(4))) float f32x4;

// Pack two fp32 into two bf16 (round-half-up) in one u32: 3 VALU ops per pair.
__device__ __forceinline__ unsigned pack2bf(float x0, float x1) {
    unsigned u0 = __float_as_uint(x0) + 0x8000u;
    unsigned u1 = __float_as_uint(x1) + 0x8000u;
    return __builtin_amdgcn_perm(u1, u0, 0x07060302u);  // {u1.hi16, u0.hi16}
}

// Convert W (mul x mul, row-major [u][w]) to bf16, fold in scale, store in
// MFMA-B-fragment order: frag (cb,kb) holds B[k][n] for n=cb*16+(l&15),
// k=kb*32+(l>>4)*8+j ; element addr = ((cb*NKB+kb)*64 + lane)*8 + j.
__device__ __forceinline__ void prep_one(const float* __restrict__ W,
                                         unsigned short* __restrict__ dst,
                                         int mul, int shift, float scale, int idx) {
    if (idx >= mul * mul) return;
    int u = idx >> shift;
    int w = idx - (u << shift);
    int nkb = mul >> 5;
    int cb = w >> 4, kb = u >> 5;
    int lane = ((u >> 3) & 3) * 16 + (w & 15);
    int j = u & 7;
    unsigned uv = __float_as_uint(W[idx] * scale) + 0x8000u;
    dst[(((cb * nkb + kb) * 64 + lane) << 3) + j] = (unsigned short)(uv >> 16);
}

// Single prep launch: blocks [0,256) -> W0, [256,320) -> W1, [320,336) -> W2.
__global__ __launch_bounds__(256) void prep_all(const float* __restrict__ W0,
                                                const float* __restrict__ W1,
                                                const float* __restrict__ W2,
                                                unsigned short* __restrict__ wf) {
    int b = blockIdx.x;
    if (b < 256)      prep_one(W0, wf,         256, 8, 0.0625f,              b * 256 + threadIdx.x);
    else if (b < 320) prep_one(W1, wf + 65536, 128, 7, 0.08838834764831845f, (b - 256) * 256 + threadIdx.x);
    else              prep_one(W2, wf + 81920, 64,  6, 0.125f,               (b - 320) * 256 + threadIdx.x);
}

// Read 2*D swizzled 16B chunks of row `lrow` starting at logical chunk c0,
// de-interleave by d into D A-fragments (elem j = x[u_octet_base + j][d]).
template <int D>
__device__ __forceinline__ void pack_from_lds(const float* __restrict__ lrow, int xr, int c0,
                                              short8* __restrict__ out) {
    float buf[8 * D];
#pragma unroll
    for (int v = 0; v < 2 * D; ++v) {
        f32x4 t = *reinterpret_cast<const f32x4*>(lrow + (((c0 + v) ^ xr) << 2));
        buf[v * 4 + 0] = t[0]; buf[v * 4 + 1] = t[1];
        buf[v * 4 + 2] = t[2]; buf[v * 4 + 3] = t[3];
    }
#pragma unroll
    for (int d = 0; d < D; ++d) {
        union { short8 s8; unsigned u[4]; } fr;
#pragma unroll
        for (int jj = 0; jj < 4; ++jj)
            fr.u[jj] = pack2bf(buf[(2 * jj) * D + d], buf[(2 * jj + 1) * D + d]);
        out[d] = fr.s8;
    }
}

// grid = 256 blocks (1/CU, LDS-limited), 4 waves/block. Block owns a contiguous
// run of 16-row tiles. T3/T4: 2-deep double buffer with COUNTED vmcnt(15) +
// raw s_barrier — next tile's 15 global_load_lds stay in flight across the
// barrier, so the HBM queue never drains to empty (kills the per-tile bubble).
__global__ __launch_bounds__(256, 1) void lin_main(const float* __restrict__ in,
                                                   const unsigned short* __restrict__ wf0,
                                                   const unsigned short* __restrict__ wf1,
                                                   const unsigned short* __restrict__ wf2,
                                                   const float* __restrict__ bias,
                                                   float* __restrict__ out) {
    __shared__ float lds[2][15360];  // 2 x 16 rows x 960 f32 = 122880 B
    const int w = threadIdx.x >> 6;
    const int lane = threadIdx.x & 63;
    const int lm = lane & 15, lg = lane >> 4, xr = lm & 7;

    // ---- register(AGPR)-resident B fragments (whole W, split by cb across waves)
    short8 b0[4][8], b1[2][4], b2[2];
#pragma unroll
    for (int c = 0; c < 4; ++c)
#pragma unroll
        for (int kb = 0; kb < 8; ++kb)
            b0[c][kb] = *reinterpret_cast<const short8*>(wf0 + ((((w * 4 + c) * 8 + kb) * 64 + lane) << 3));
#pragma unroll
    for (int c = 0; c < 2; ++c)
#pragma unroll
        for (int kb = 0; kb < 4; ++kb)
            b1[c][kb] = *reinterpret_cast<const short8*>(wf1 + ((((w * 2 + c) * 4 + kb) * 64 + lane) << 3));
#pragma unroll
    for (int kb = 0; kb < 2; ++kb)
        b2[kb] = *reinterpret_cast<const short8*>(wf2 + (((w * 2 + kb) * 64 + lane) << 3));
    float bv[4];
#pragma unroll
    for (int c = 0; c < 4; ++c) bv[c] = bias[(w * 4 + c) * 16 + lm];

    // ---- per-lane staging source offsets (bytes from tile base), pre-swizzled:
    // LDS slot (row,c) <- global chunk (row, c ^ (row&7)); slot = w*960 + i*64 + lane.
    int srcoff[15];
#pragma unroll
    for (int i = 0; i < 15; ++i) {
        int s = w * 960 + i * 64 + lane;
        int row = (int)(((long long)s * 17477) >> 22);  // s / 240
        int c = s - row * 240;
        srcoff[i] = (row * 240 + (c ^ (row & 7))) << 4;
    }

    const int b = blockIdx.x;
    const int nt = (b < 106) ? 25 : 24;          // 6250 tiles over 256 blocks
    const int t0 = b * 24 + (b < 106 ? b : 106); // contiguous tile range

#define STAGE(kk, bufi)                                                                   \
    {                                                                                     \
        const char* tb = (const char*)in + (size_t)(t0 + (kk)) * 61440;                   \
        char* sd = (char*)&lds[0][0] + (bufi) * 61440 + w * 15360;                        \
        _Pragma("unroll")                                                                 \
        for (int i = 0; i < 15; ++i)                                                      \
            __builtin_amdgcn_global_load_lds(                                             \
                (const __attribute__((address_space(1))) void*)(tb + srcoff[i]),          \
                (__attribute__((address_space(3))) void*)(sd + i * 1024), 16, 0, 0);      \
    }

    // ---- prologue: stage tile 0 (15 loads in flight)
    STAGE(0, 0);

    for (int k = 0; k < nt; ++k) {
        const int par = k & 1;
        if (k + 1 < nt) {
            STAGE(k + 1, par ^ 1);
            asm volatile("s_waitcnt vmcnt(15)" ::: "memory");  // stage(k) resident; stage(k+1) in flight
        } else {
            asm volatile("s_waitcnt vmcnt(0)" ::: "memory");
        }
        __builtin_amdgcn_s_barrier();          // all waves' stage(k) resident
        __builtin_amdgcn_sched_barrier(0);

        // ---- compute current tile from LDS
        const float* lrow = &lds[0][0] + par * 15360 + lm * 960;
        const int trow = (t0 + k) * 16;
        {  // blk0: MUL=256, D=1, cols [0,256), bias
            short8 a[8];
#pragma unroll
            for (int kb = 0; kb < 8; ++kb)
                pack_from_lds<1>(lrow, xr, 8 * kb + 2 * lg, &a[kb]);
#pragma unroll
            for (int c = 0; c < 4; ++c) {
                f32x4 acc = {0.f, 0.f, 0.f, 0.f};
#pragma unroll
                for (int kb = 0; kb < 8; ++kb)
                    acc = __builtin_amdgcn_mfma_f32_16x16x32_bf16(a[kb], b0[c][kb], acc, 0, 0, 0);
#pragma unroll
                for (int jj = 0; jj < 4; ++jj)
                    out[(size_t)(trow + lg * 4 + jj) * 960 + (w * 4 + c) * 16 + lm] = acc[jj] + bv[c];
            }
        }
        {  // blk1: MUL=128, D=3, cols [256,640)
            short8 a[4][3];
#pragma unroll
            for (int kb = 0; kb < 4; ++kb)
                pack_from_lds<3>(lrow, xr, 64 + 24 * kb + 6 * lg, a[kb]);
#pragma unroll
            for (int c = 0; c < 2; ++c) {
                f32x4 acc[3];
#pragma unroll
                for (int d = 0; d < 3; ++d) acc[d] = (f32x4){0.f, 0.f, 0.f, 0.f};
#pragma unroll
                for (int kb = 0; kb < 4; ++kb)
#pragma unroll
                    for (int d = 0; d < 3; ++d)
                        acc[d] = __builtin_amdgcn_mfma_f32_16x16x32_bf16(a[kb][d], b1[c][kb], acc[d], 0, 0, 0);
#pragma unroll
                for (int jj = 0; jj < 4; ++jj) {
                    float* op = out + (size_t)(trow + lg * 4 + jj) * 960 + 256 + ((w * 2 + c) * 16 + lm) * 3;
#pragma unroll
                    for (int d = 0; d < 3; ++d) op[d] = acc[d][jj];
                }
            }
        }
        {  // blk2: MUL=64, D=5, cols [640,960)
            short8 a[2][5];
#pragma unroll
            for (int kb = 0; kb < 2; ++kb)
                pack_from_lds<5>(lrow, xr, 160 + 40 * kb + 10 * lg, a[kb]);
            f32x4 acc[5];
#pragma unroll
            for (int d = 0; d < 5; ++d) acc[d] = (f32x4){0.f, 0.f, 0.f, 0.f};
#pragma unroll
            for (int kb = 0; kb < 2; ++kb)
#pragma unroll
                for (int d = 0; d < 5; ++d)
                    acc[d] = __builtin_amdgcn_mfma_f32_16x16x32_bf16(a[kb][d], b2[kb], acc[d], 0, 0, 0);
#pragma unroll
            for (int jj = 0; jj < 4; ++jj) {
                float* op = out + (size_t)(trow + lg * 4 + jj) * 960 + 640 + (w * 16 + lm) * 5;
#pragma unroll
                for (int d = 0; d < 5; ++d) op[d] = acc[d][jj];
            }
        }

        __builtin_amdgcn_sched_barrier(0);
        __builtin_amdgcn_s_barrier();  // raw barrier (NO drain): buf[par] free for stage(k+2)
    }
#undef STAGE
}

extern "C" void kernel_launch(void* const* d_in, const int* in_sizes, int n_in,
                              void* d_out, int out_size, void* d_ws, size_t ws_size,
                              hipStream_t stream) {
    (void)in_sizes; (void)n_in; (void)out_size; (void)ws_size;
    const float* x  = (const float*)d_in[0];
    const float* W0 = (const float*)d_in[1];
    const float* W1 = (const float*)d_in[2];
    const float* W2 = (const float*)d_in[3];
    const float* b  = (const float*)d_in[4];
    float* out = (float*)d_out;
    unsigned short* wf = (unsigned short*)d_ws;  // 65536 + 16384 + 4096 bf16 = 168 KB

    prep_all<<<336, 256, 0, stream>>>(W0, W1, W2, wf);
    lin_main<<<256, 256, 0, stream>>>(x, wf, wf + 65536, wf + 81920, b, out);
}